// Round 7
// baseline (297.326 us; speedup 1.0000x reference)
//
#include <hip/hip_runtime.h>
#include <math.h>

// ============================================================================
// Round 22: knn only.
//  (a) phase-1 min accumulation rewritten as left-nested fmin chain so clang
//      fuses to v_min3_f32 (2 ops per 4 candidates vs 4). Exact min is
//      association-free => identical gmins.
//  (b) phase-2 interleave widened 2->4: one loop drives all 4 rows of a wave
//      (4 gathers in flight, 4 independent ballot chains per step, 4-stream
//      bitonic sort). Per-row extraction order ascending == serial version
//      => bit-identical output. VGPR ~56 under the 64 cap (lb 1024,8).
// ============================================================================

#define EPSBN 1e-5f

typedef _Float16 v8h  __attribute__((ext_vector_type(8)));
typedef _Float16 v4h  __attribute__((ext_vector_type(4)));
typedef float    v16f __attribute__((ext_vector_type(16)));

// ---- ws layout (float offsets) ----
#define W0T_OFF   0         // [3][64]
#define B0_OFF    192
#define W1T_OFF   256       // [64][64]
#define B1_OFF    4352
#define A0XT_OFF  4416      // [3][64]
#define A0FT_OFF  4608      // [64][64]
#define BA0_OFF   8704
#define A1T_OFF   8768      // fp16 frag-linear a1 image (8192 halfs)
#define BA1_OFF   16960
#define A2T_OFF   17088     // fp16 frag-linear a2 image (16384 halfs)
#define BA2_OFF   33472
#define C2T_OFF   33600     // fp16 frag-linear c2 image: 8192 float4
#define C3H_OFF   66368     // fp16 frag-linear c3 image: 4096 float4
#define BC2_OFF   99136
#define BC3_OFF   132160
#define C4T_OFF   132288    // [128][6] fp32
#define BC4_OFF   133056
#define PTS4_OFF  133120    // [32768] float4 {x,y,z,sq}
#define Q_OFF     264192    // [32768][64]
#define C_OFF     2361344   // [32768][64]
#define IDX_OFF   4458496   // [32768][16] int (batch-local m)
#define LOCAL_OFF 4982784   // [32768][128]
#define GF_OFF    9177088   // [8][128]

// ---------------------------------------------------------------------------
// Kernel 0: fold BN into weights + zero GF (memset dispatch folded in).
// ---------------------------------------------------------------------------
__device__ __forceinline__ void fold_one(int e, const float* w, const float* b,
    const float* g, const float* t, const float* m, const float* v,
    float* wt, float* bo, int O, int Cfull, int cbeg)
{
    int o = e % O, c = e / O;
    float s = 1.0f;
    if (g) s = g[o] * (1.0f / sqrtf(v[o] + EPSBN));
    wt[c * O + o] = w[o * Cfull + cbeg + c] * s;
    if (c == 0 && bo) {
        float bias = b[o];
        if (g) bias = (bias - m[o]) * s + t[o];
        bo[o] = bias;
    }
}

__global__ __launch_bounds__(256) void fold_kernel(
    const float* c0w, const float* c0b, const float* c0g, const float* c0t, const float* c0m, const float* c0v,
    const float* c1w, const float* c1b, const float* c1g, const float* c1t, const float* c1m, const float* c1v,
    const float* a0w, const float* a0b, const float* a0g, const float* a0t, const float* a0m, const float* a0v,
    const float* a1w, const float* a1b, const float* a1g, const float* a1t, const float* a1m, const float* a1v,
    const float* a2w, const float* a2b, const float* a2g, const float* a2t, const float* a2m, const float* a2v,
    const float* c2w, const float* c2b, const float* c2g, const float* c2t, const float* c2m, const float* c2v,
    const float* c3w, const float* c3b, const float* c3g, const float* c3t, const float* c3m, const float* c3v,
    const float* c4w, const float* c4b,
    float* ws)
{
    int e = blockIdx.x * 256 + threadIdx.x;
    if (e < 192)        { fold_one(e,          c0w, c0b, c0g, c0t, c0m, c0v, ws + W0T_OFF,  ws + B0_OFF,  64, 3,   0); return; }
    e -= 192;
    if (e < 4096)       { fold_one(e,          c1w, c1b, c1g, c1t, c1m, c1v, ws + W1T_OFF,  ws + B1_OFF,  64, 64,  0); return; }
    e -= 4096;
    if (e < 192)        { fold_one(e,          a0w, a0b, a0g, a0t, a0m, a0v, ws + A0XT_OFF, ws + BA0_OFF, 64, 67,  0); return; }
    e -= 192;
    if (e < 4096)       { fold_one(e,          a0w, a0b, a0g, a0t, a0m, a0v, ws + A0FT_OFF, nullptr,      64, 67,  3); return; }
    e -= 4096;
    if (e < 8192) {
        int j = e & 7, l = (e >> 3) & 63, kf = (e >> 9) & 3, wv = e >> 11;
        int o = wv * 32 + (l & 31);
        int c = kf * 16 + (l >> 5) * 8 + j;
        float s = a1g[o] * (1.0f / sqrtf(a1v[o] + EPSBN));
        ((_Float16*)(ws + A1T_OFF))[e] = (_Float16)(a1w[o * 64 + c] * s);
        if (c == 0) ws[BA1_OFF + o] = (a1b[o] - a1m[o]) * s + a1t[o];
        return;
    }
    e -= 8192;
    if (e < 16384) {
        int j = e & 7, l = (e >> 3) & 63, kf = (e >> 9) & 7, wv = e >> 12;
        int o = wv * 32 + (l & 31);
        int c = kf * 16 + (l >> 5) * 8 + j;
        float s = a2g[o] * (1.0f / sqrtf(a2v[o] + EPSBN));
        ((_Float16*)(ws + A2T_OFF))[e] = (_Float16)(a2w[o * 128 + c] * s);
        if (c == 0) ws[BA2_OFF + o] = (a2b[o] - a2m[o]) * s + a2t[o];
        return;
    }
    e -= 16384;
    if (e < 65536) {
        int j = e & 7, l = (e >> 3) & 63, s5 = (e >> 9) & 15, ot = e >> 13;
        int o = ot * 32 + (l & 31);
        int c = s5 * 16 + (l >> 5) * 8 + j;
        float sc = c2g[o] * (1.0f / sqrtf(c2v[o] + EPSBN));
        ((_Float16*)(ws + C2T_OFF))[e] = (_Float16)(c2w[o * 256 + c] * sc);
        if (c == 0) ws[BC2_OFF + o] = (c2b[o] - c2m[o]) * sc + c2t[o];
        return;
    }
    e -= 65536;
    if (e < 32768) {
        int j = e & 7, l = (e >> 3) & 63, s5 = (e >> 9) & 15, ot = e >> 13;
        int o = ot * 32 + (l & 31);
        int c = s5 * 16 + (l >> 5) * 8 + j;
        float sc = c3g[o] * (1.0f / sqrtf(c3v[o] + EPSBN));
        ((_Float16*)(ws + C3H_OFF))[e] = (_Float16)(c3w[o * 256 + c] * sc);
        if (c == 0) ws[BC3_OFF + o] = (c3b[o] - c3m[o]) * sc + c3t[o];
        return;
    }
    e -= 32768;
    if (e < 768)        { fold_one(e,          c4w, c4b, nullptr, nullptr, nullptr, nullptr, ws + C4T_OFF, ws + BC4_OFF, 6, 128, 0); return; }
    e -= 768;
    if (e < 1024)       { ws[GF_OFF + e] = 0.0f; return; }   // GF zero (was memset)
}

// ---------------------------------------------------------------------------
// Kernel 1 (v3): per-point MLP 3->64->64, 4 points per WAVE (16 pts/block).
// ---------------------------------------------------------------------------
__global__ __launch_bounds__(256) void point_mlp_kernel(const float* __restrict__ pts, float* __restrict__ ws)
{
    __shared__ float sh[4][64][4];   // [wave][c][point]
    __shared__ float sx[4][64][4];
    int lane = threadIdx.x & 63;
    int wv = threadIdx.x >> 6;
    int pid0 = blockIdx.x * 16 + wv * 4;

    // 12 uniform coord loads (compiler -> s_load)
    const float* pc = pts + (size_t)pid0 * 3;
    float c0x = pc[0], c0y = pc[1],  c0z = pc[2];
    float c1x = pc[3], c1y = pc[4],  c1z = pc[5];
    float c2x = pc[6], c2y = pc[7],  c2z = pc[8];
    float c3x = pc[9], c3y = pc[10], c3z = pc[11];

    if (lane < 4) {
        const float* pp = pts + (size_t)(pid0 + lane) * 3;
        float xx = pp[0], yy = pp[1], zz = pp[2];
        float sq = __fadd_rn(__fadd_rn(__fmul_rn(xx, xx), __fmul_rn(yy, yy)), __fmul_rn(zz, zz));
        ((float4*)(ws + PTS4_OFF))[pid0 + lane] = make_float4(xx, yy, zz, sq);
    }

    const float* W0T  = ws + W0T_OFF;
    const float* B0   = ws + B0_OFF;
    const float* W1T  = ws + W1T_OFF;
    const float* B1   = ws + B1_OFF;
    const float* A0XT = ws + A0XT_OFF;
    const float* A0FT = ws + A0FT_OFF;
    const float* BA0  = ws + BA0_OFF;

    // layer 0: 3 -> 64 (weights loaded once, used for 4 points)
    float b0 = B0[lane];
    float w0a = W0T[lane], w0b = W0T[64 + lane], w0c = W0T[128 + lane];
    float4 h;
    h.x = fmaxf(fmaf(c0z, w0c, fmaf(c0y, w0b, fmaf(c0x, w0a, b0))), 0.0f);
    h.y = fmaxf(fmaf(c1z, w0c, fmaf(c1y, w0b, fmaf(c1x, w0a, b0))), 0.0f);
    h.z = fmaxf(fmaf(c2z, w0c, fmaf(c2y, w0b, fmaf(c2x, w0a, b0))), 0.0f);
    h.w = fmaxf(fmaf(c3z, w0c, fmaf(c3y, w0b, fmaf(c3x, w0a, b0))), 0.0f);
    *(float4*)&sh[wv][lane][0] = h;

    // layer 1: 64 -> 64
    float b1v = B1[lane];
    float a0 = b1v, a1 = b1v, a2 = b1v, a3 = b1v;
    #pragma unroll 8
    for (int c = 0; c < 64; ++c) {
        float w = W1T[c * 64 + lane];
        float4 hv = *(const float4*)&sh[wv][c][0];   // uniform addr -> broadcast
        a0 = fmaf(w, hv.x, a0);
        a1 = fmaf(w, hv.y, a1);
        a2 = fmaf(w, hv.z, a2);
        a3 = fmaf(w, hv.w, a3);
    }
    float4 xv;
    xv.x = fmaxf(a0, 0.0f);
    xv.y = fmaxf(a1, 0.0f);
    xv.z = fmaxf(a2, 0.0f);
    xv.w = fmaxf(a3, 0.0f);
    *(float4*)&sx[wv][lane][0] = xv;

    // Q = A0X * p  (per point)
    float ax = A0XT[lane], ay = A0XT[64 + lane], az = A0XT[128 + lane];
    float q0 = __fmul_rn(c0x, ax); q0 = fmaf(c0y, ay, q0); q0 = fmaf(c0z, az, q0);
    float q1 = __fmul_rn(c1x, ax); q1 = fmaf(c1y, ay, q1); q1 = fmaf(c1z, az, q1);
    float q2 = __fmul_rn(c2x, ax); q2 = fmaf(c2y, ay, q2); q2 = fmaf(c2z, az, q2);
    float q3 = __fmul_rn(c3x, ax); q3 = fmaf(c3y, ay, q3); q3 = fmaf(c3z, az, q3);
    ws[Q_OFF + (size_t)(pid0 + 0) * 64 + lane] = q0;
    ws[Q_OFF + (size_t)(pid0 + 1) * 64 + lane] = q1;
    ws[Q_OFF + (size_t)(pid0 + 2) * 64 + lane] = q2;
    ws[Q_OFF + (size_t)(pid0 + 3) * 64 + lane] = q3;

    // C = A0F * x1 + bias  (per point)
    float ba = BA0[lane];
    float e0 = q0 + ba, e1 = q1 + ba, e2 = q2 + ba, e3 = q3 + ba;
    #pragma unroll 8
    for (int c = 0; c < 64; ++c) {
        float w = A0FT[c * 64 + lane];
        float4 sv = *(const float4*)&sx[wv][c][0];
        e0 = fmaf(w, sv.x, e0);
        e1 = fmaf(w, sv.y, e1);
        e2 = fmaf(w, sv.z, e2);
        e3 = fmaf(w, sv.w, e3);
    }
    ws[C_OFF + (size_t)(pid0 + 0) * 64 + lane] = e0;
    ws[C_OFF + (size_t)(pid0 + 1) * 64 + lane] = e1;
    ws[C_OFF + (size_t)(pid0 + 2) * 64 + lane] = e2;
    ws[C_OFF + (size_t)(pid0 + 3) * 64 + lane] = e3;
}

// ---------------------------------------------------------------------------
// Kernel 2: exact kNN, 64 rows / 1024 thr / 16 waves, grid 512.
// Phase 2: 4-way interleaved scan + sort (R22).
// ---------------------------------------------------------------------------
__device__ __forceinline__ float dist2_ref(float xn, float yn, float zn, float sqn, float4 pm)
{
    float dot = __fmul_rn(xn, pm.x);
    dot = __fmaf_rn(yn, pm.y, dot);
    dot = __fmaf_rn(zn, pm.z, dot);
    float s = __fadd_rn(sqn, pm.w);
    // fma(-2,dot,s) == s - round(2*dot) bitwise: 2*dot is exact in fp32.
    return __fmaf_rn(-2.0f, dot, s);
}

// phase-1 metric: sqm - 2*dot  (row-constant +sqn deferred)
__device__ __forceinline__ float dtilde(float xn, float yn, float zn, float4 pm)
{
    float dot = __fmul_rn(xn, pm.x);
    dot = __fmaf_rn(yn, pm.y, dot);
    dot = __fmaf_rn(zn, pm.z, dot);
    return __fmaf_rn(-2.0f, dot, pm.w);
}

#define KNN_CAP 64
#define KNN_MARGIN 1e-3f   // >> max rounding delta (~3e-5) between dtilde+sr and dist2_ref

// Four rows' ballot+scan+sort, interleaved (independent chains overlap 4x).
// Per-row group extraction order is ascending == the serial version =>
// identical buffer contents => identical sort output.
__device__ __forceinline__ void knn_quad(
    const float4* __restrict__ pts4, int* __restrict__ IDX,
    float* __restrict__ bd0, int* __restrict__ bi0,
    float* __restrict__ bd1, int* __restrict__ bi1,
    float* __restrict__ bd2, int* __restrict__ bi2,
    float* __restrict__ bd3, int* __restrict__ bi3,
    int* __restrict__ cntp,
    int base, int rg0, int l,
    float gm0, float gm1, float gm2, float gm3,
    float tvd0, float tvd1, float tvd2, float tvd3)
{
    float4 p0 = pts4[rg0 + 0];
    float4 p1 = pts4[rg0 + 1];
    float4 p2 = pts4[rg0 + 2];
    float4 p3 = pts4[rg0 + 3];
    float tve0 = __fadd_rn(p0.w, tvd0);
    float tve1 = __fadd_rn(p1.w, tvd1);
    float tve2 = __fadd_rn(p2.w, tvd2);
    float tve3 = __fadd_rn(p3.w, tvd3);
    unsigned long long q0 = __ballot(gm0 <= tvd0);
    unsigned long long q1 = __ballot(gm1 <= tvd1);
    unsigned long long q2 = __ballot(gm2 <= tvd2);
    unsigned long long q3 = __ballot(gm3 <= tvd3);
    int cr0 = 0, cr1 = 0, cr2 = 0, cr3 = 0;

    #define KNN_PROC4(GG, CV, PP, TVE, CR, BD, BI)                             \
    {                                                                          \
        float d = dist2_ref((PP).x, (PP).y, (PP).z, (PP).w, (CV));             \
        bool p = ((GG) >= 0) & (d <= (TVE));                                   \
        unsigned long long mk = __ballot(p);                                   \
        int my = __builtin_amdgcn_mbcnt_hi((unsigned)(mk >> 32),               \
                 __builtin_amdgcn_mbcnt_lo((unsigned)mk, 0));                  \
        int slot = (CR) + my;                                                  \
        if (p && slot < KNN_CAP) { (BD)[slot] = d; (BI)[slot] = (GG) * 64 + l; } \
        (CR) += (int)__popcll(mk);                                             \
    }
    while (q0 | q1 | q2 | q3) {
        int g0 = -1, g1 = -1, g2 = -1, g3 = -1;
        if (q0) { g0 = __ffsll((unsigned long long)q0) - 1; q0 &= q0 - 1; }
        if (q1) { g1 = __ffsll((unsigned long long)q1) - 1; q1 &= q1 - 1; }
        if (q2) { g2 = __ffsll((unsigned long long)q2) - 1; q2 &= q2 - 1; }
        if (q3) { g3 = __ffsll((unsigned long long)q3) - 1; q3 &= q3 - 1; }
        float4 c0, c1, c2, c3;
        if (g0 >= 0) c0 = pts4[base + g0 * 64 + l];
        if (g1 >= 0) c1 = pts4[base + g1 * 64 + l];
        if (g2 >= 0) c2 = pts4[base + g2 * 64 + l];
        if (g3 >= 0) c3 = pts4[base + g3 * 64 + l];
        KNN_PROC4(g0, c0, p0, tve0, cr0, bd0, bi0);
        KNN_PROC4(g1, c1, p1, tve1, cr1, bd1, bi1);
        KNN_PROC4(g2, c2, p2, tve2, cr2, bd2, bi2);
        KNN_PROC4(g3, c3, p3, tve3, cr3, bd3, bi3);
    }
    #undef KNN_PROC4
    if (l == 0) { cntp[0] = cr0; cntp[1] = cr1; cntp[2] = cr2; cntp[3] = cr3; }

    unsigned long long k0 = ~0ULL, k1 = ~0ULL, k2 = ~0ULL, k3 = ~0ULL;
    if (l < cr0) {
        unsigned u = __float_as_uint(bd0[l]);
        u = (u & 0x80000000u) ? ~u : (u | 0x80000000u);
        k0 = ((unsigned long long)u << 32) | (unsigned)bi0[l];
    }
    if (l < cr1) {
        unsigned u = __float_as_uint(bd1[l]);
        u = (u & 0x80000000u) ? ~u : (u | 0x80000000u);
        k1 = ((unsigned long long)u << 32) | (unsigned)bi1[l];
    }
    if (l < cr2) {
        unsigned u = __float_as_uint(bd2[l]);
        u = (u & 0x80000000u) ? ~u : (u | 0x80000000u);
        k2 = ((unsigned long long)u << 32) | (unsigned)bi2[l];
    }
    if (l < cr3) {
        unsigned u = __float_as_uint(bd3[l]);
        u = (u & 0x80000000u) ? ~u : (u | 0x80000000u);
        k3 = ((unsigned long long)u << 32) | (unsigned)bi3[l];
    }
    int crm = cr0 > cr1 ? cr0 : cr1;
    if (cr2 > crm) crm = cr2;
    if (cr3 > crm) crm = cr3;
    // Width selection is perf-only: a width-64 network on keys confined to
    // lanes 0..31 (rest ~0ULL) yields the same sorted prefix.
    if (crm <= 32) {
        #pragma unroll
        for (int k = 2; k <= 32; k <<= 1) {
            #pragma unroll
            for (int j = k >> 1; j > 0; j >>= 1) {
                unsigned long long o0 = __shfl_xor(k0, j);
                unsigned long long o1 = __shfl_xor(k1, j);
                unsigned long long o2 = __shfl_xor(k2, j);
                unsigned long long o3 = __shfl_xor(k3, j);
                bool mx = (((l & j) != 0) == ((l & k) == 0));
                k0 = mx ? (k0 > o0 ? k0 : o0) : (k0 < o0 ? k0 : o0);
                k1 = mx ? (k1 > o1 ? k1 : o1) : (k1 < o1 ? k1 : o1);
                k2 = mx ? (k2 > o2 ? k2 : o2) : (k2 < o2 ? k2 : o2);
                k3 = mx ? (k3 > o3 ? k3 : o3) : (k3 < o3 ? k3 : o3);
            }
        }
    } else {
        #pragma unroll
        for (int k = 2; k <= 64; k <<= 1) {
            #pragma unroll
            for (int j = k >> 1; j > 0; j >>= 1) {
                unsigned long long o0 = __shfl_xor(k0, j);
                unsigned long long o1 = __shfl_xor(k1, j);
                unsigned long long o2 = __shfl_xor(k2, j);
                unsigned long long o3 = __shfl_xor(k3, j);
                bool mx = (((l & j) != 0) == ((l & k) == 0));
                k0 = mx ? (k0 > o0 ? k0 : o0) : (k0 < o0 ? k0 : o0);
                k1 = mx ? (k1 > o1 ? k1 : o1) : (k1 < o1 ? k1 : o1);
                k2 = mx ? (k2 > o2 ? k2 : o2) : (k2 < o2 ? k2 : o2);
                k3 = mx ? (k3 > o3 ? k3 : o3) : (k3 < o3 ? k3 : o3);
            }
        }
    }
    if (l < 16) {
        if (cr0 <= KNN_CAP) IDX[(rg0 + 0) * 16 + l] = (int)(k0 & 0xFFFFFFFFu);
        if (cr1 <= KNN_CAP) IDX[(rg0 + 1) * 16 + l] = (int)(k1 & 0xFFFFFFFFu);
        if (cr2 <= KNN_CAP) IDX[(rg0 + 2) * 16 + l] = (int)(k2 & 0xFFFFFFFFu);
        if (cr3 <= KNN_CAP) IDX[(rg0 + 3) * 16 + l] = (int)(k3 & 0xFFFFFFFFu);
    }
}

__global__ __launch_bounds__(1024, 8) void knn_kernel(float* __restrict__ ws)
{
    __shared__ float gmins[64 * 65];
    __shared__ float bufd[16][4][72];
    __shared__ int   bufi[16][4][72];
    __shared__ int   cnt[64];

    const float4* __restrict__ pts4 = (const float4*)(ws + PTS4_OFF);
    int* IDX = (int*)(ws + IDX_OFF);

    const int l     = threadIdx.x & 63;
    const int row   = l;
    const int wvu   = __builtin_amdgcn_readfirstlane(threadIdx.x >> 6);
    const int base  = (blockIdx.x >> 6) << 12;
    const int rbase = blockIdx.x * 64;
    const int r     = rbase + row;

    float4 pn = pts4[r];
    float xn = pn.x, yn = pn.y, zn = pn.z;

    // phase 1: wave-uniform candidate address (s_load broadcast), dtilde metric.
    // Left-nested fmin chain -> v_min3 fusion; exact min is association-free.
    #pragma unroll
    for (int g = 0; g < 4; ++g) {
        const float4* __restrict__ cp = pts4 + base + wvu * 256 + g * 64;
        float mn = INFINITY;
        #pragma unroll 4
        for (int i = 0; i < 64; i += 4) {
            float d0 = dtilde(xn, yn, zn, cp[i + 0]);
            float d1 = dtilde(xn, yn, zn, cp[i + 1]);
            float d2 = dtilde(xn, yn, zn, cp[i + 2]);
            float d3 = dtilde(xn, yn, zn, cp[i + 3]);
            mn = fminf(mn, fminf(fminf(fminf(d0, d1), d2), d3));
        }
        gmins[row * 65 + wvu * 4 + g] = mn;
    }
    __syncthreads();

    // interleaved 4-row threshold ladder (same VALU count, dep-latency /4)
    float gm0 = gmins[(wvu * 4 + 0) * 65 + l];
    float gm1 = gmins[(wvu * 4 + 1) * 65 + l];
    float gm2 = gmins[(wvu * 4 + 2) * 65 + l];
    float gm3 = gmins[(wvu * 4 + 3) * 65 + l];
    float v0 = gm0, v1 = gm1, v2 = gm2, v3 = gm3;
    #pragma unroll
    for (int k = 2; k <= 64; k <<= 1) {
        #pragma unroll
        for (int j = k >> 1; j > 0; j >>= 1) {
            float o0 = __shfl_xor(v0, j);
            float o1 = __shfl_xor(v1, j);
            float o2 = __shfl_xor(v2, j);
            float o3 = __shfl_xor(v3, j);
            bool mx = (((l & j) != 0) == ((l & k) == 0));
            v0 = mx ? fmaxf(v0, o0) : fminf(v0, o0);
            v1 = mx ? fmaxf(v1, o1) : fminf(v1, o1);
            v2 = mx ? fmaxf(v2, o2) : fminf(v2, o2);
            v3 = mx ? fmaxf(v3, o3) : fminf(v3, o3);
        }
    }
    float tvd0 = __shfl(v0, 16) + KNN_MARGIN;
    float tvd1 = __shfl(v1, 16) + KNN_MARGIN;
    float tvd2 = __shfl(v2, 16) + KNN_MARGIN;
    float tvd3 = __shfl(v3, 16) + KNN_MARGIN;

    knn_quad(pts4, IDX,
             &bufd[wvu][0][0], &bufi[wvu][0][0], &bufd[wvu][1][0], &bufi[wvu][1][0],
             &bufd[wvu][2][0], &bufi[wvu][2][0], &bufd[wvu][3][0], &bufi[wvu][3][0],
             &cnt[wvu * 4], base, rbase + wvu * 4, l,
             gm0, gm1, gm2, gm3, tvd0, tvd1, tvd2, tvd3);
    __syncthreads();

    if (threadIdx.x < 64 && cnt[threadIdx.x] > KNN_CAP) {
        int* out = IDX + (rbase + threadIdx.x) * 16;
        float4 pq = pts4[rbase + threadIdx.x];
        float hd[16]; int hi[16];
        #pragma unroll
        for (int t2 = 0; t2 < 16; ++t2) { hd[t2] = INFINITY; hi[t2] = 0; }
        for (int mm = 0; mm < 4096; ++mm) {
            float d = dist2_ref(pq.x, pq.y, pq.z, pq.w, pts4[base + mm]);
            if (d < hd[15]) {
                float vd = d; int vi = mm;
                #pragma unroll
                for (int t2 = 0; t2 < 16; ++t2) {
                    bool sm = vd < hd[t2];
                    float td = hd[t2]; int ti = hi[t2];
                    if (sm) { hd[t2] = vd; hi[t2] = vi; vd = td; vi = ti; }
                }
            }
        }
        for (int jj = 0; jj < 16; ++jj) out[jj] = hi[jj];
    }
}

// ---------------------------------------------------------------------------
// Kernel 3: a1+a2 fp16 MFMA; a2 operand-swapped (row=neighbor, col=channel)
// with register-space pooling + fused global-feature atomicMax epilogue.
// ---------------------------------------------------------------------------
__device__ __forceinline__ void nbr_stage_g1(
    _Float16* sG1, const float* Cf, const float* Qf,
    int t, int gpt0, int g, int base, int m)
{
    int r = t >> 2, cs = t & 3;
    int gpt = gpt0 + g * 4 + (r >> 4);
    const float4* crow = (const float4*)(Cf + (size_t)(base + m) * 64) + cs * 4;
    const float4* qrow = (const float4*)(Qf + (size_t)gpt * 64) + cs * 4;
    v8h h0, h1;
    #pragma unroll
    for (int u = 0; u < 2; ++u) {
        float4 cv = crow[u], qv = qrow[u];
        h0[u * 4 + 0] = (_Float16)fmaxf(cv.x - qv.x, 0.0f);
        h0[u * 4 + 1] = (_Float16)fmaxf(cv.y - qv.y, 0.0f);
        h0[u * 4 + 2] = (_Float16)fmaxf(cv.z - qv.z, 0.0f);
        h0[u * 4 + 3] = (_Float16)fmaxf(cv.w - qv.w, 0.0f);
    }
    #pragma unroll
    for (int u = 0; u < 2; ++u) {
        float4 cv = crow[2 + u], qv = qrow[2 + u];
        h1[u * 4 + 0] = (_Float16)fmaxf(cv.x - qv.x, 0.0f);
        h1[u * 4 + 1] = (_Float16)fmaxf(cv.y - qv.y, 0.0f);
        h1[u * 4 + 2] = (_Float16)fmaxf(cv.z - qv.z, 0.0f);
        h1[u * 4 + 3] = (_Float16)fmaxf(cv.w - qv.w, 0.0f);
    }
    int rs = r & 7;
    *(v8h*)&sG1[r * 64 + ((cs * 2    ) ^ rs) * 8] = h0;
    *(v8h*)&sG1[r * 64 + ((cs * 2 + 1) ^ rs) * 8] = h1;
}

__global__ __launch_bounds__(256) void nbr_mlp_mfma_kernel(float* __restrict__ ws)
{
    __shared__ __align__(16) unsigned char smem[33280];
    _Float16* sG1   = (_Float16*)smem;             //  8192 B
    _Float16* sH1   = (_Float16*)(smem + 8192);    // 16384 B
    float*    sPool = (float*)(smem + 24576);      //  8192 B
    float*    sB1   = (float*)(smem + 32768);      //   512 B

    const int t   = threadIdx.x;
    const int l   = t & 63;
    const int w   = t >> 6;
    const int ln  = l & 31;
    const int hi  = l >> 5;
    const int blk = blockIdx.x;
    const int gpt0 = blk * 16;
    const int base = (blk >> 8) << 12;

    const float* Cf = ws + C_OFF;
    const float* Qf = ws + Q_OFF;
    const int* IDX = (const int*)(ws + IDX_OFF);

    if (t < 128) sB1[t] = ws[BA1_OFF + t];
    // a2 bias for this lane's output channel (col=lane&31 after operand swap)
    float b2ch = ws[BA2_OFF + w * 32 + ln];

    int mi[4];
    {
        int r = t >> 2;
        #pragma unroll
        for (int g = 0; g < 4; ++g)
            mi[g] = IDX[(gpt0 + g * 4 + (r >> 4)) * 16 + (r & 15)];
    }

    v8h fa[4], fa2[8];
    {
        const float4* a1img = (const float4*)(ws + A1T_OFF);
        const float4* a2img = (const float4*)(ws + A2T_OFF);
        #pragma unroll
        for (int kf = 0; kf < 4; ++kf) {
            float4 tmp = a1img[(w * 4 + kf) * 64 + l];
            fa[kf] = *(v8h*)&tmp;
        }
        #pragma unroll
        for (int kf = 0; kf < 8; ++kf) {
            float4 tmp = a2img[(w * 8 + kf) * 64 + l];
            fa2[kf] = *(v8h*)&tmp;
        }
    }

    nbr_stage_g1(sG1, Cf, Qf, t, gpt0, 0, base, mi[0]);
    __syncthreads();

    for (int g = 0; g < 4; ++g) {
        // ---- a1: channels in D-rows (regs), neighbors in D-cols (lanes) ----
        #pragma unroll
        for (int rt = 0; rt < 2; ++rt) {
            int r = rt * 32 + ln, rs = r & 7;
            v16f acc;
            #pragma unroll
            for (int i = 0; i < 16; ++i) acc[i] = 0.0f;
            #pragma unroll
            for (int kf = 0; kf < 4; ++kf) {
                v8h fb = *(const v8h*)&sG1[r * 64 + ((kf * 2 + hi) ^ rs) * 8];
                acc = __builtin_amdgcn_mfma_f32_32x32x16_f16(fa[kf], fb, acc, 0, 0, 0);
            }
            #pragma unroll
            for (int q = 0; q < 4; ++q) {
                float4 b4 = *(const float4*)&sB1[w * 32 + 8 * q + 4 * hi];
                v4h hv;
                hv[0] = (_Float16)fmaxf(acc[q * 4 + 0] + b4.x, 0.0f);
                hv[1] = (_Float16)fmaxf(acc[q * 4 + 1] + b4.y, 0.0f);
                hv[2] = (_Float16)fmaxf(acc[q * 4 + 2] + b4.z, 0.0f);
                hv[3] = (_Float16)fmaxf(acc[q * 4 + 3] + b4.w, 0.0f);
                int gg = w * 4 + q;
                *(v4h*)&sH1[r * 128 + ((gg ^ rs) * 8) + 4 * hi] = hv;
            }
        }
        __syncthreads();

        if (g < 3) nbr_stage_g1(sG1, Cf, Qf, t, gpt0, g + 1, base, mi[g + 1]);

        // ---- a2 SWAPPED: mfma(data, weights) => D row=neighbor, col=channel.
        #pragma unroll
        for (int rt = 0; rt < 2; ++rt) {
            int r = rt * 32 + ln, rs = r & 7;
            v16f acc;
            #pragma unroll
            for (int i = 0; i < 16; ++i) acc[i] = 0.0f;
            #pragma unroll
            for (int kf = 0; kf < 8; ++kf) {
                v8h fb = *(const v8h*)&sH1[r * 128 + ((kf * 2 + hi) ^ rs) * 8];
                acc = __builtin_amdgcn_mfma_f32_32x32x16_f16(fb, fa2[kf], acc, 0, 0, 0);
            }
            // pool over 16 neighbors = D-rows
            float p0 = acc[0], p1 = acc[8];
            #pragma unroll
            for (int i = 1; i < 8; ++i) { p0 = fmaxf(p0, acc[i]); p1 = fmaxf(p1, acc[8 + i]); }
            p0 = fmaxf(p0, __shfl_xor(p0, 32));
            p1 = fmaxf(p1, __shfl_xor(p1, 32));
            float o0 = fmaxf(p0 + b2ch, 0.0f);
            float o1 = fmaxf(p1 + b2ch, 0.0f);
            if (hi == 0) {
                int p = g * 4 + rt * 2;
                sPool[p * 128 + w * 32 + ln]       = o0;
                sPool[(p + 1) * 128 + w * 32 + ln] = o1;
            }
        }
        __syncthreads();
    }

    {
        float* LOCAL = ws + LOCAL_OFF;
        const float4* sp4 = (const float4*)sPool;
        #pragma unroll
        for (int u = 0; u < 2; ++u) {
            int e = t + 256 * u;
            int pp = e >> 5, cc = e & 31;
            ((float4*)&LOCAL[(size_t)(gpt0 + pp) * 128])[cc] = sp4[e];
        }
    }

    if (t < 128) {
        float m = 0.0f;
        #pragma unroll
        for (int p = 0; p < 16; ++p) m = fmaxf(m, sPool[p * 128 + t]);
        atomicMax((int*)(ws + GF_OFF) + (blk >> 8) * 128 + t, __float_as_int(m));
    }
}

// ---------------------------------------------------------------------------
// Kernel 5: head c2/c3 fp16 MFMA + c4 fp32 — 8 waves/block (512 thr).
// ---------------------------------------------------------------------------
__global__ __launch_bounds__(512) void head_mfma_kernel(float* __restrict__ ws, float* __restrict__ out)
{
    __shared__ __align__(16) unsigned char smem[66560];
    _Float16* sF  = (_Float16*)smem;
    float*    sF3 = (float*)smem;
    _Float16* sF2 = (_Float16*)(smem + 33792);

    const int t  = threadIdx.x;
    const int l  = t & 63;
    const int w  = t >> 6;           // 0..7
    const int ln = l & 31;
    const int hi = l >> 5;
    const int gpt0 = blockIdx.x * 64;
    const int b = blockIdx.x >> 6;

    const float4* c2h = (const float4*)(ws + C2T_OFF);
    const float4* c3h = (const float4*)(ws + C3H_OFF);

    {
        int m = t >> 3, cs = t & 7;
        const float4* src = (cs < 4)
            ? (const float4*)(ws + LOCAL_OFF + (size_t)(gpt0 + m) * 128) + cs * 8
            : (const float4*)(ws + GF_OFF + b * 128) + (cs - 4) * 8;
        int gbase = cs * 4;
        #pragma unroll
        for (int u = 0; u < 4; ++u) {
            float4 a0 = src[u * 2], a1 = src[u * 2 + 1];
            v8h h;
            h[0] = (_Float16)a0.x; h[1] = (_Float16)a0.y;
            h[2] = (_Float16)a0.z; h[3] = (_Float16)a0.w;
            h[4] = (_Float16)a1.x; h[5] = (_Float16)a1.y;
            h[6] = (_Float16)a1.z; h[7] = (_Float16)a1.w;
            int g = (gbase + u) ^ (m & 31);
            *(v8h*)&sF[m * 256 + g * 8] = h;
        }
    }
    __syncthreads();

    // c2: one output tile per wave (ot2 = w, 0..7)
    {
        v8h fa[16];
        #pragma unroll
        for (int s = 0; s < 16; ++s) {
            float4 tmp = c2h[(w * 16 + s) * 64 + l];
            fa[s] = *(v8h*)&tmp;
        }
        float b2[16];
        #pragma unroll
        for (int i = 0; i < 16; ++i)
            b2[i] = ws[BC2_OFF + w * 32 + (i & 3) + 8 * (i >> 2) + 4 * hi];
        #pragma unroll
        for (int mt = 0; mt < 2; ++mt) {
            int m = mt * 32 + ln;
            v16f acc;
            #pragma unroll
            for (int i = 0; i < 16; ++i) acc[i] = 0.0f;
            #pragma unroll
            for (int s = 0; s < 16; ++s) {
                v8h fb = *(const v8h*)&sF[m * 256 + (((2 * s + hi) ^ ln) * 8)];
                acc = __builtin_amdgcn_mfma_f32_32x32x16_f16(fa[s], fb, acc, 0, 0, 0);
            }
            #pragma unroll
            for (int q = 0; q < 4; ++q) {
                v4h hv;
                #pragma unroll
                for (int j = 0; j < 4; ++j)
                    hv[j] = (_Float16)fmaxf(acc[q * 4 + j] + b2[q * 4 + j], 0.0f);
                *(v4h*)&sF2[m * 256 + (((w * 4 + q) ^ ln) * 8) + 4 * hi] = hv;
            }
        }
    }
    __syncthreads();

    // c3: (tile, m-half) = (w>>1, w&1)
    {
        int tw = w >> 1, mt = w & 1;
        v8h fa[16];
        #pragma unroll
        for (int s = 0; s < 16; ++s) {
            float4 tmp = c3h[(tw * 16 + s) * 64 + l];
            fa[s] = *(v8h*)&tmp;
        }
        float b3[16];
        #pragma unroll
        for (int i = 0; i < 16; ++i)
            b3[i] = ws[BC3_OFF + tw * 32 + (i & 3) + 8 * (i >> 2) + 4 * hi];
        int m = mt * 32 + ln;
        v16f acc;
        #pragma unroll
        for (int i = 0; i < 16; ++i) acc[i] = 0.0f;
        #pragma unroll
        for (int s = 0; s < 16; ++s) {
            v8h fb = *(const v8h*)&sF2[m * 256 + (((2 * s + hi) ^ ln) * 8)];
            acc = __builtin_amdgcn_mfma_f32_32x32x16_f16(fa[s], fb, acc, 0, 0, 0);
        }
        #pragma unroll
        for (int q = 0; q < 4; ++q) {
            float4 hv;
            hv.x = fmaxf(acc[q * 4 + 0] + b3[q * 4 + 0], 0.0f);
            hv.y = fmaxf(acc[q * 4 + 1] + b3[q * 4 + 1], 0.0f);
            hv.z = fmaxf(acc[q * 4 + 2] + b3[q * 4 + 2], 0.0f);
            hv.w = fmaxf(acc[q * 4 + 3] + b3[q * 4 + 3], 0.0f);
            *(float4*)&sF3[m * 132 + tw * 32 + q * 8 + 4 * hi] = hv;
        }
    }
    __syncthreads();

    const float* C4T = ws + C4T_OFF;
    for (int mo = t; mo < 384; mo += 512) {
        int m = mo / 6, o = mo - m * 6;
        float a = ws[BC4_OFF + o];
        const float4* f4 = (const float4*)(sF3 + m * 132);
        #pragma unroll 8
        for (int kq = 0; kq < 32; ++kq) {
            float4 f = f4[kq];
            a = fmaf(f.x, C4T[(kq * 4 + 0) * 6 + o], a);
            a = fmaf(f.y, C4T[(kq * 4 + 1) * 6 + o], a);
            a = fmaf(f.z, C4T[(kq * 4 + 2) * 6 + o], a);
            a = fmaf(f.w, C4T[(kq * 4 + 3) * 6 + o], a);
        }
        out[(size_t)(gpt0 + m) * 6 + o] = a;
    }
}

// ---------------------------------------------------------------------------
extern "C" void kernel_launch(void* const* d_in, const int* in_sizes, int n_in,
                              void* d_out, int out_size, void* d_ws, size_t ws_size,
                              hipStream_t stream)
{
    const float* pts = (const float*)d_in[0];
    float* ws = (float*)d_ws;
    float* out = (float*)d_out;

    fold_kernel<<<521, 256, 0, stream>>>(
        (const float*)d_in[1],  (const float*)d_in[2],  (const float*)d_in[3],  (const float*)d_in[4],  (const float*)d_in[5],  (const float*)d_in[6],
        (const float*)d_in[7],  (const float*)d_in[8],  (const float*)d_in[9],  (const float*)d_in[10], (const float*)d_in[11], (const float*)d_in[12],
        (const float*)d_in[13], (const float*)d_in[14], (const float*)d_in[15], (const float*)d_in[16], (const float*)d_in[17], (const float*)d_in[18],
        (const float*)d_in[19], (const float*)d_in[20], (const float*)d_in[21], (const float*)d_in[22], (const float*)d_in[23], (const float*)d_in[24],
        (const float*)d_in[25], (const float*)d_in[26], (const float*)d_in[27], (const float*)d_in[28], (const float*)d_in[29], (const float*)d_in[30],
        (const float*)d_in[31], (const float*)d_in[32], (const float*)d_in[33], (const float*)d_in[34], (const float*)d_in[35], (const float*)d_in[36],
        (const float*)d_in[37], (const float*)d_in[38], (const float*)d_in[39], (const float*)d_in[40], (const float*)d_in[41], (const float*)d_in[42],
        (const float*)d_in[43], (const float*)d_in[44],
        ws);

    point_mlp_kernel<<<2048, 256, 0, stream>>>(pts, ws);
    knn_kernel<<<512, 1024, 0, stream>>>(ws);
    nbr_mlp_mfma_kernel<<<2048, 256, 0, stream>>>(ws);
    head_mfma_kernel<<<512, 512, 0, stream>>>(ws, out);
}

// Round 9
// 283.478 us; speedup vs baseline: 1.0488x; 1.0488x over previous
//
#include <hip/hip_runtime.h>
#include <math.h>

// ============================================================================
// Round 24: resubmit of R21-best (283.6us measured) after R23's infra-only
// bench failure (container acquisition, not kernel). Components:
//  - knn phase 1: 4 independent dtilde accumulators, wave-uniform s_load.
//  - knn phase 2: PAIRWISE interleaved scan+sort (widest fit in 64 VGPRs;
//    R22 proved 4-way crosses the spill cliff: VALUBusy 75->59).
//  - nbr_mlp: a2 operand swap + register pooling (R20).
//  - head_mfma: 8 waves/block (R21).
// ============================================================================

#define EPSBN 1e-5f

typedef _Float16 v8h  __attribute__((ext_vector_type(8)));
typedef _Float16 v4h  __attribute__((ext_vector_type(4)));
typedef float    v16f __attribute__((ext_vector_type(16)));

// ---- ws layout (float offsets) ----
#define W0T_OFF   0         // [3][64]
#define B0_OFF    192
#define W1T_OFF   256       // [64][64]
#define B1_OFF    4352
#define A0XT_OFF  4416      // [3][64]
#define A0FT_OFF  4608      // [64][64]
#define BA0_OFF   8704
#define A1T_OFF   8768      // fp16 frag-linear a1 image (8192 halfs)
#define BA1_OFF   16960
#define A2T_OFF   17088     // fp16 frag-linear a2 image (16384 halfs)
#define BA2_OFF   33472
#define C2T_OFF   33600     // fp16 frag-linear c2 image: 8192 float4
#define C3H_OFF   66368     // fp16 frag-linear c3 image: 4096 float4
#define BC2_OFF   99136
#define BC3_OFF   132160
#define C4T_OFF   132288    // [128][6] fp32
#define BC4_OFF   133056
#define PTS4_OFF  133120    // [32768] float4 {x,y,z,sq}
#define Q_OFF     264192    // [32768][64]
#define C_OFF     2361344   // [32768][64]
#define IDX_OFF   4458496   // [32768][16] int (batch-local m)
#define LOCAL_OFF 4982784   // [32768][128]
#define GF_OFF    9177088   // [8][128]

// ---------------------------------------------------------------------------
// Kernel 0: fold BN into weights + zero GF (memset dispatch folded in).
// ---------------------------------------------------------------------------
__device__ __forceinline__ void fold_one(int e, const float* w, const float* b,
    const float* g, const float* t, const float* m, const float* v,
    float* wt, float* bo, int O, int Cfull, int cbeg)
{
    int o = e % O, c = e / O;
    float s = 1.0f;
    if (g) s = g[o] * (1.0f / sqrtf(v[o] + EPSBN));
    wt[c * O + o] = w[o * Cfull + cbeg + c] * s;
    if (c == 0 && bo) {
        float bias = b[o];
        if (g) bias = (bias - m[o]) * s + t[o];
        bo[o] = bias;
    }
}

__global__ __launch_bounds__(256) void fold_kernel(
    const float* c0w, const float* c0b, const float* c0g, const float* c0t, const float* c0m, const float* c0v,
    const float* c1w, const float* c1b, const float* c1g, const float* c1t, const float* c1m, const float* c1v,
    const float* a0w, const float* a0b, const float* a0g, const float* a0t, const float* a0m, const float* a0v,
    const float* a1w, const float* a1b, const float* a1g, const float* a1t, const float* a1m, const float* a1v,
    const float* a2w, const float* a2b, const float* a2g, const float* a2t, const float* a2m, const float* a2v,
    const float* c2w, const float* c2b, const float* c2g, const float* c2t, const float* c2m, const float* c2v,
    const float* c3w, const float* c3b, const float* c3g, const float* c3t, const float* c3m, const float* c3v,
    const float* c4w, const float* c4b,
    float* ws)
{
    int e = blockIdx.x * 256 + threadIdx.x;
    if (e < 192)        { fold_one(e,          c0w, c0b, c0g, c0t, c0m, c0v, ws + W0T_OFF,  ws + B0_OFF,  64, 3,   0); return; }
    e -= 192;
    if (e < 4096)       { fold_one(e,          c1w, c1b, c1g, c1t, c1m, c1v, ws + W1T_OFF,  ws + B1_OFF,  64, 64,  0); return; }
    e -= 4096;
    if (e < 192)        { fold_one(e,          a0w, a0b, a0g, a0t, a0m, a0v, ws + A0XT_OFF, ws + BA0_OFF, 64, 67,  0); return; }
    e -= 192;
    if (e < 4096)       { fold_one(e,          a0w, a0b, a0g, a0t, a0m, a0v, ws + A0FT_OFF, nullptr,      64, 67,  3); return; }
    e -= 4096;
    if (e < 8192) {
        int j = e & 7, l = (e >> 3) & 63, kf = (e >> 9) & 3, wv = e >> 11;
        int o = wv * 32 + (l & 31);
        int c = kf * 16 + (l >> 5) * 8 + j;
        float s = a1g[o] * (1.0f / sqrtf(a1v[o] + EPSBN));
        ((_Float16*)(ws + A1T_OFF))[e] = (_Float16)(a1w[o * 64 + c] * s);
        if (c == 0) ws[BA1_OFF + o] = (a1b[o] - a1m[o]) * s + a1t[o];
        return;
    }
    e -= 8192;
    if (e < 16384) {
        int j = e & 7, l = (e >> 3) & 63, kf = (e >> 9) & 7, wv = e >> 12;
        int o = wv * 32 + (l & 31);
        int c = kf * 16 + (l >> 5) * 8 + j;
        float s = a2g[o] * (1.0f / sqrtf(a2v[o] + EPSBN));
        ((_Float16*)(ws + A2T_OFF))[e] = (_Float16)(a2w[o * 128 + c] * s);
        if (c == 0) ws[BA2_OFF + o] = (a2b[o] - a2m[o]) * s + a2t[o];
        return;
    }
    e -= 16384;
    if (e < 65536) {
        int j = e & 7, l = (e >> 3) & 63, s5 = (e >> 9) & 15, ot = e >> 13;
        int o = ot * 32 + (l & 31);
        int c = s5 * 16 + (l >> 5) * 8 + j;
        float sc = c2g[o] * (1.0f / sqrtf(c2v[o] + EPSBN));
        ((_Float16*)(ws + C2T_OFF))[e] = (_Float16)(c2w[o * 256 + c] * sc);
        if (c == 0) ws[BC2_OFF + o] = (c2b[o] - c2m[o]) * sc + c2t[o];
        return;
    }
    e -= 65536;
    if (e < 32768) {
        int j = e & 7, l = (e >> 3) & 63, s5 = (e >> 9) & 15, ot = e >> 13;
        int o = ot * 32 + (l & 31);
        int c = s5 * 16 + (l >> 5) * 8 + j;
        float sc = c3g[o] * (1.0f / sqrtf(c3v[o] + EPSBN));
        ((_Float16*)(ws + C3H_OFF))[e] = (_Float16)(c3w[o * 256 + c] * sc);
        if (c == 0) ws[BC3_OFF + o] = (c3b[o] - c3m[o]) * sc + c3t[o];
        return;
    }
    e -= 32768;
    if (e < 768)        { fold_one(e,          c4w, c4b, nullptr, nullptr, nullptr, nullptr, ws + C4T_OFF, ws + BC4_OFF, 6, 128, 0); return; }
    e -= 768;
    if (e < 1024)       { ws[GF_OFF + e] = 0.0f; return; }   // GF zero (was memset)
}

// ---------------------------------------------------------------------------
// Kernel 1 (v3): per-point MLP 3->64->64, 4 points per WAVE (16 pts/block).
// ---------------------------------------------------------------------------
__global__ __launch_bounds__(256) void point_mlp_kernel(const float* __restrict__ pts, float* __restrict__ ws)
{
    __shared__ float sh[4][64][4];   // [wave][c][point]
    __shared__ float sx[4][64][4];
    int lane = threadIdx.x & 63;
    int wv = threadIdx.x >> 6;
    int pid0 = blockIdx.x * 16 + wv * 4;

    // 12 uniform coord loads (compiler -> s_load)
    const float* pc = pts + (size_t)pid0 * 3;
    float c0x = pc[0], c0y = pc[1],  c0z = pc[2];
    float c1x = pc[3], c1y = pc[4],  c1z = pc[5];
    float c2x = pc[6], c2y = pc[7],  c2z = pc[8];
    float c3x = pc[9], c3y = pc[10], c3z = pc[11];

    if (lane < 4) {
        const float* pp = pts + (size_t)(pid0 + lane) * 3;
        float xx = pp[0], yy = pp[1], zz = pp[2];
        float sq = __fadd_rn(__fadd_rn(__fmul_rn(xx, xx), __fmul_rn(yy, yy)), __fmul_rn(zz, zz));
        ((float4*)(ws + PTS4_OFF))[pid0 + lane] = make_float4(xx, yy, zz, sq);
    }

    const float* W0T  = ws + W0T_OFF;
    const float* B0   = ws + B0_OFF;
    const float* W1T  = ws + W1T_OFF;
    const float* B1   = ws + B1_OFF;
    const float* A0XT = ws + A0XT_OFF;
    const float* A0FT = ws + A0FT_OFF;
    const float* BA0  = ws + BA0_OFF;

    // layer 0: 3 -> 64 (weights loaded once, used for 4 points)
    float b0 = B0[lane];
    float w0a = W0T[lane], w0b = W0T[64 + lane], w0c = W0T[128 + lane];
    float4 h;
    h.x = fmaxf(fmaf(c0z, w0c, fmaf(c0y, w0b, fmaf(c0x, w0a, b0))), 0.0f);
    h.y = fmaxf(fmaf(c1z, w0c, fmaf(c1y, w0b, fmaf(c1x, w0a, b0))), 0.0f);
    h.z = fmaxf(fmaf(c2z, w0c, fmaf(c2y, w0b, fmaf(c2x, w0a, b0))), 0.0f);
    h.w = fmaxf(fmaf(c3z, w0c, fmaf(c3y, w0b, fmaf(c3x, w0a, b0))), 0.0f);
    *(float4*)&sh[wv][lane][0] = h;

    // layer 1: 64 -> 64
    float b1v = B1[lane];
    float a0 = b1v, a1 = b1v, a2 = b1v, a3 = b1v;
    #pragma unroll 8
    for (int c = 0; c < 64; ++c) {
        float w = W1T[c * 64 + lane];
        float4 hv = *(const float4*)&sh[wv][c][0];   // uniform addr -> broadcast
        a0 = fmaf(w, hv.x, a0);
        a1 = fmaf(w, hv.y, a1);
        a2 = fmaf(w, hv.z, a2);
        a3 = fmaf(w, hv.w, a3);
    }
    float4 xv;
    xv.x = fmaxf(a0, 0.0f);
    xv.y = fmaxf(a1, 0.0f);
    xv.z = fmaxf(a2, 0.0f);
    xv.w = fmaxf(a3, 0.0f);
    *(float4*)&sx[wv][lane][0] = xv;

    // Q = A0X * p  (per point)
    float ax = A0XT[lane], ay = A0XT[64 + lane], az = A0XT[128 + lane];
    float q0 = __fmul_rn(c0x, ax); q0 = fmaf(c0y, ay, q0); q0 = fmaf(c0z, az, q0);
    float q1 = __fmul_rn(c1x, ax); q1 = fmaf(c1y, ay, q1); q1 = fmaf(c1z, az, q1);
    float q2 = __fmul_rn(c2x, ax); q2 = fmaf(c2y, ay, q2); q2 = fmaf(c2z, az, q2);
    float q3 = __fmul_rn(c3x, ax); q3 = fmaf(c3y, ay, q3); q3 = fmaf(c3z, az, q3);
    ws[Q_OFF + (size_t)(pid0 + 0) * 64 + lane] = q0;
    ws[Q_OFF + (size_t)(pid0 + 1) * 64 + lane] = q1;
    ws[Q_OFF + (size_t)(pid0 + 2) * 64 + lane] = q2;
    ws[Q_OFF + (size_t)(pid0 + 3) * 64 + lane] = q3;

    // C = A0F * x1 + bias  (per point)
    float ba = BA0[lane];
    float e0 = q0 + ba, e1 = q1 + ba, e2 = q2 + ba, e3 = q3 + ba;
    #pragma unroll 8
    for (int c = 0; c < 64; ++c) {
        float w = A0FT[c * 64 + lane];
        float4 sv = *(const float4*)&sx[wv][c][0];
        e0 = fmaf(w, sv.x, e0);
        e1 = fmaf(w, sv.y, e1);
        e2 = fmaf(w, sv.z, e2);
        e3 = fmaf(w, sv.w, e3);
    }
    ws[C_OFF + (size_t)(pid0 + 0) * 64 + lane] = e0;
    ws[C_OFF + (size_t)(pid0 + 1) * 64 + lane] = e1;
    ws[C_OFF + (size_t)(pid0 + 2) * 64 + lane] = e2;
    ws[C_OFF + (size_t)(pid0 + 3) * 64 + lane] = e3;
}

// ---------------------------------------------------------------------------
// Kernel 2: exact kNN, 64 rows / 1024 thr / 16 waves, grid 512.
// Phase 2: pairwise-interleaved scan + sort (R21, proven 62.3us).
// ---------------------------------------------------------------------------
__device__ __forceinline__ float dist2_ref(float xn, float yn, float zn, float sqn, float4 pm)
{
    float dot = __fmul_rn(xn, pm.x);
    dot = __fmaf_rn(yn, pm.y, dot);
    dot = __fmaf_rn(zn, pm.z, dot);
    float s = __fadd_rn(sqn, pm.w);
    // fma(-2,dot,s) == s - round(2*dot) bitwise: 2*dot is exact in fp32.
    return __fmaf_rn(-2.0f, dot, s);
}

// phase-1 metric: sqm - 2*dot  (row-constant +sqn deferred; 5 VALU w/ fmin)
__device__ __forceinline__ float dtilde(float xn, float yn, float zn, float4 pm)
{
    float dot = __fmul_rn(xn, pm.x);
    dot = __fmaf_rn(yn, pm.y, dot);
    dot = __fmaf_rn(zn, pm.z, dot);
    return __fmaf_rn(-2.0f, dot, pm.w);
}

#define KNN_CAP 64
#define KNN_MARGIN 1e-3f   // >> max rounding delta (~3e-5) between dtilde+sr and dist2_ref

// Two rows' ballot+scan+sort, interleaved (independent chains overlap).
// Per-row group extraction order is ascending == the serial version =>
// identical buffer contents => identical sort output.
__device__ __forceinline__ void knn_pair(
    const float4* __restrict__ pts4, int* __restrict__ IDX,
    float* __restrict__ bdA, int* __restrict__ biA,
    float* __restrict__ bdB, int* __restrict__ biB,
    int* __restrict__ cntA, int* __restrict__ cntB,
    int base, int rgA, int rgB, int l,
    float gmA, float gmB, float tvdA, float tvdB)
{
    float4 pA = pts4[rgA];
    float4 pB = pts4[rgB];
    float tveA = __fadd_rn(pA.w, tvdA);
    float tveB = __fadd_rn(pB.w, tvdB);
    unsigned long long qA = __ballot(gmA <= tvdA);
    unsigned long long qB = __ballot(gmB <= tvdB);
    int crA = 0, crB = 0;

    #define KNN_PROC2(GG, CV, PP, TVE, CR, BD, BI)                             \
    {                                                                          \
        float d = dist2_ref((PP).x, (PP).y, (PP).z, (PP).w, (CV));             \
        bool p = ((GG) >= 0) & (d <= (TVE));                                   \
        unsigned long long mk = __ballot(p);                                   \
        int my = __builtin_amdgcn_mbcnt_hi((unsigned)(mk >> 32),               \
                 __builtin_amdgcn_mbcnt_lo((unsigned)mk, 0));                  \
        int slot = (CR) + my;                                                  \
        if (p && slot < KNN_CAP) { (BD)[slot] = d; (BI)[slot] = (GG) * 64 + l; } \
        (CR) += (int)__popcll(mk);                                             \
    }
    while (qA | qB) {
        int a0 = -1, a1 = -1, b0 = -1, b1 = -1;
        if (qA) { a0 = __ffsll((unsigned long long)qA) - 1; qA &= qA - 1;
            if (qA) { a1 = __ffsll((unsigned long long)qA) - 1; qA &= qA - 1; } }
        if (qB) { b0 = __ffsll((unsigned long long)qB) - 1; qB &= qB - 1;
            if (qB) { b1 = __ffsll((unsigned long long)qB) - 1; qB &= qB - 1; } }
        float4 ca0, ca1, cb0, cb1;
        if (a0 >= 0) ca0 = pts4[base + a0 * 64 + l];
        if (b0 >= 0) cb0 = pts4[base + b0 * 64 + l];
        if (a1 >= 0) ca1 = pts4[base + a1 * 64 + l];
        if (b1 >= 0) cb1 = pts4[base + b1 * 64 + l];
        KNN_PROC2(a0, ca0, pA, tveA, crA, bdA, biA);
        KNN_PROC2(b0, cb0, pB, tveB, crB, bdB, biB);
        KNN_PROC2(a1, ca1, pA, tveA, crA, bdA, biA);
        KNN_PROC2(b1, cb1, pB, tveB, crB, bdB, biB);
    }
    #undef KNN_PROC2
    if (l == 0) { *cntA = crA; *cntB = crB; }

    unsigned long long kA = ~0ULL, kB = ~0ULL;
    if (l < crA) {
        unsigned u = __float_as_uint(bdA[l]);
        u = (u & 0x80000000u) ? ~u : (u | 0x80000000u);
        kA = ((unsigned long long)u << 32) | (unsigned)biA[l];
    }
    if (l < crB) {
        unsigned u = __float_as_uint(bdB[l]);
        u = (u & 0x80000000u) ? ~u : (u | 0x80000000u);
        kB = ((unsigned long long)u << 32) | (unsigned)biB[l];
    }
    int crm = crA > crB ? crA : crB;
    if (crm <= 32) {
        #pragma unroll
        for (int k = 2; k <= 32; k <<= 1) {
            #pragma unroll
            for (int j = k >> 1; j > 0; j >>= 1) {
                unsigned long long oA = __shfl_xor(kA, j);
                unsigned long long oB = __shfl_xor(kB, j);
                bool mx = (((l & j) != 0) == ((l & k) == 0));
                kA = mx ? (kA > oA ? kA : oA) : (kA < oA ? kA : oA);
                kB = mx ? (kB > oB ? kB : oB) : (kB < oB ? kB : oB);
            }
        }
    } else {
        #pragma unroll
        for (int k = 2; k <= 64; k <<= 1) {
            #pragma unroll
            for (int j = k >> 1; j > 0; j >>= 1) {
                unsigned long long oA = __shfl_xor(kA, j);
                unsigned long long oB = __shfl_xor(kB, j);
                bool mx = (((l & j) != 0) == ((l & k) == 0));
                kA = mx ? (kA > oA ? kA : oA) : (kA < oA ? kA : oA);
                kB = mx ? (kB > oB ? kB : oB) : (kB < oB ? kB : oB);
            }
        }
    }
    if (l < 16) {
        if (crA <= KNN_CAP) IDX[rgA * 16 + l] = (int)(kA & 0xFFFFFFFFu);
        if (crB <= KNN_CAP) IDX[rgB * 16 + l] = (int)(kB & 0xFFFFFFFFu);
    }
}

__global__ __launch_bounds__(1024, 8) void knn_kernel(float* __restrict__ ws)
{
    __shared__ float gmins[64 * 65];
    __shared__ float bufd[16][4][72];
    __shared__ int   bufi[16][4][72];
    __shared__ int   cnt[64];

    const float4* __restrict__ pts4 = (const float4*)(ws + PTS4_OFF);
    int* IDX = (int*)(ws + IDX_OFF);

    const int l     = threadIdx.x & 63;
    const int row   = l;
    const int wvu   = __builtin_amdgcn_readfirstlane(threadIdx.x >> 6);
    const int base  = (blockIdx.x >> 6) << 12;
    const int rbase = blockIdx.x * 64;
    const int r     = rbase + row;

    float4 pn = pts4[r];
    float xn = pn.x, yn = pn.y, zn = pn.z;

    // phase 1: wave-uniform candidate address (s_load broadcast), dtilde metric.
    #pragma unroll
    for (int g = 0; g < 4; ++g) {
        const float4* __restrict__ cp = pts4 + base + wvu * 256 + g * 64;
        float mn0 = INFINITY, mn1 = INFINITY, mn2 = INFINITY, mn3 = INFINITY;
        #pragma unroll 4
        for (int i = 0; i < 64; i += 4) {
            mn0 = fminf(mn0, dtilde(xn, yn, zn, cp[i + 0]));
            mn1 = fminf(mn1, dtilde(xn, yn, zn, cp[i + 1]));
            mn2 = fminf(mn2, dtilde(xn, yn, zn, cp[i + 2]));
            mn3 = fminf(mn3, dtilde(xn, yn, zn, cp[i + 3]));
        }
        gmins[row * 65 + wvu * 4 + g] = fminf(fminf(mn0, mn1), fminf(mn2, mn3));
    }
    __syncthreads();

    // interleaved 4-row threshold ladder (same VALU count, dep-latency /4)
    float gm0 = gmins[(wvu * 4 + 0) * 65 + l];
    float gm1 = gmins[(wvu * 4 + 1) * 65 + l];
    float gm2 = gmins[(wvu * 4 + 2) * 65 + l];
    float gm3 = gmins[(wvu * 4 + 3) * 65 + l];
    float v0 = gm0, v1 = gm1, v2 = gm2, v3 = gm3;
    #pragma unroll
    for (int k = 2; k <= 64; k <<= 1) {
        #pragma unroll
        for (int j = k >> 1; j > 0; j >>= 1) {
            float o0 = __shfl_xor(v0, j);
            float o1 = __shfl_xor(v1, j);
            float o2 = __shfl_xor(v2, j);
            float o3 = __shfl_xor(v3, j);
            bool mx = (((l & j) != 0) == ((l & k) == 0));
            v0 = mx ? fmaxf(v0, o0) : fminf(v0, o0);
            v1 = mx ? fmaxf(v1, o1) : fminf(v1, o1);
            v2 = mx ? fmaxf(v2, o2) : fminf(v2, o2);
            v3 = mx ? fmaxf(v3, o3) : fminf(v3, o3);
        }
    }
    float tvd0 = __shfl(v0, 16) + KNN_MARGIN;
    float tvd1 = __shfl(v1, 16) + KNN_MARGIN;
    float tvd2 = __shfl(v2, 16) + KNN_MARGIN;
    float tvd3 = __shfl(v3, 16) + KNN_MARGIN;

    knn_pair(pts4, IDX, &bufd[wvu][0][0], &bufi[wvu][0][0], &bufd[wvu][1][0], &bufi[wvu][1][0],
             &cnt[wvu * 4 + 0], &cnt[wvu * 4 + 1], base,
             rbase + wvu * 4 + 0, rbase + wvu * 4 + 1, l, gm0, gm1, tvd0, tvd1);
    knn_pair(pts4, IDX, &bufd[wvu][2][0], &bufi[wvu][2][0], &bufd[wvu][3][0], &bufi[wvu][3][0],
             &cnt[wvu * 4 + 2], &cnt[wvu * 4 + 3], base,
             rbase + wvu * 4 + 2, rbase + wvu * 4 + 3, l, gm2, gm3, tvd2, tvd3);
    __syncthreads();

    if (threadIdx.x < 64 && cnt[threadIdx.x] > KNN_CAP) {
        int* out = IDX + (rbase + threadIdx.x) * 16;
        float4 pq = pts4[rbase + threadIdx.x];
        float hd[16]; int hi[16];
        #pragma unroll
        for (int t2 = 0; t2 < 16; ++t2) { hd[t2] = INFINITY; hi[t2] = 0; }
        for (int mm = 0; mm < 4096; ++mm) {
            float d = dist2_ref(pq.x, pq.y, pq.z, pq.w, pts4[base + mm]);
            if (d < hd[15]) {
                float vd = d; int vi = mm;
                #pragma unroll
                for (int t2 = 0; t2 < 16; ++t2) {
                    bool sm = vd < hd[t2];
                    float td = hd[t2]; int ti = hi[t2];
                    if (sm) { hd[t2] = vd; hi[t2] = vi; vd = td; vi = ti; }
                }
            }
        }
        for (int jj = 0; jj < 16; ++jj) out[jj] = hi[jj];
    }
}

// ---------------------------------------------------------------------------
// Kernel 3: a1+a2 fp16 MFMA; a2 operand-swapped (row=neighbor, col=channel)
// with register-space pooling + fused global-feature atomicMax epilogue.
// ---------------------------------------------------------------------------
__device__ __forceinline__ void nbr_stage_g1(
    _Float16* sG1, const float* Cf, const float* Qf,
    int t, int gpt0, int g, int base, int m)
{
    int r = t >> 2, cs = t & 3;
    int gpt = gpt0 + g * 4 + (r >> 4);
    const float4* crow = (const float4*)(Cf + (size_t)(base + m) * 64) + cs * 4;
    const float4* qrow = (const float4*)(Qf + (size_t)gpt * 64) + cs * 4;
    v8h h0, h1;
    #pragma unroll
    for (int u = 0; u < 2; ++u) {
        float4 cv = crow[u], qv = qrow[u];
        h0[u * 4 + 0] = (_Float16)fmaxf(cv.x - qv.x, 0.0f);
        h0[u * 4 + 1] = (_Float16)fmaxf(cv.y - qv.y, 0.0f);
        h0[u * 4 + 2] = (_Float16)fmaxf(cv.z - qv.z, 0.0f);
        h0[u * 4 + 3] = (_Float16)fmaxf(cv.w - qv.w, 0.0f);
    }
    #pragma unroll
    for (int u = 0; u < 2; ++u) {
        float4 cv = crow[2 + u], qv = qrow[2 + u];
        h1[u * 4 + 0] = (_Float16)fmaxf(cv.x - qv.x, 0.0f);
        h1[u * 4 + 1] = (_Float16)fmaxf(cv.y - qv.y, 0.0f);
        h1[u * 4 + 2] = (_Float16)fmaxf(cv.z - qv.z, 0.0f);
        h1[u * 4 + 3] = (_Float16)fmaxf(cv.w - qv.w, 0.0f);
    }
    int rs = r & 7;
    *(v8h*)&sG1[r * 64 + ((cs * 2    ) ^ rs) * 8] = h0;
    *(v8h*)&sG1[r * 64 + ((cs * 2 + 1) ^ rs) * 8] = h1;
}

__global__ __launch_bounds__(256) void nbr_mlp_mfma_kernel(float* __restrict__ ws)
{
    __shared__ __align__(16) unsigned char smem[33280];
    _Float16* sG1   = (_Float16*)smem;             //  8192 B
    _Float16* sH1   = (_Float16*)(smem + 8192);    // 16384 B
    float*    sPool = (float*)(smem + 24576);      //  8192 B
    float*    sB1   = (float*)(smem + 32768);      //   512 B

    const int t   = threadIdx.x;
    const int l   = t & 63;
    const int w   = t >> 6;
    const int ln  = l & 31;
    const int hi  = l >> 5;
    const int blk = blockIdx.x;
    const int gpt0 = blk * 16;
    const int base = (blk >> 8) << 12;

    const float* Cf = ws + C_OFF;
    const float* Qf = ws + Q_OFF;
    const int* IDX = (const int*)(ws + IDX_OFF);

    if (t < 128) sB1[t] = ws[BA1_OFF + t];
    // a2 bias for this lane's output channel (col=lane&31 after operand swap)
    float b2ch = ws[BA2_OFF + w * 32 + ln];

    int mi[4];
    {
        int r = t >> 2;
        #pragma unroll
        for (int g = 0; g < 4; ++g)
            mi[g] = IDX[(gpt0 + g * 4 + (r >> 4)) * 16 + (r & 15)];
    }

    v8h fa[4], fa2[8];
    {
        const float4* a1img = (const float4*)(ws + A1T_OFF);
        const float4* a2img = (const float4*)(ws + A2T_OFF);
        #pragma unroll
        for (int kf = 0; kf < 4; ++kf) {
            float4 tmp = a1img[(w * 4 + kf) * 64 + l];
            fa[kf] = *(v8h*)&tmp;
        }
        #pragma unroll
        for (int kf = 0; kf < 8; ++kf) {
            float4 tmp = a2img[(w * 8 + kf) * 64 + l];
            fa2[kf] = *(v8h*)&tmp;
        }
    }

    nbr_stage_g1(sG1, Cf, Qf, t, gpt0, 0, base, mi[0]);
    __syncthreads();

    for (int g = 0; g < 4; ++g) {
        // ---- a1: channels in D-rows (regs), neighbors in D-cols (lanes) ----
        #pragma unroll
        for (int rt = 0; rt < 2; ++rt) {
            int r = rt * 32 + ln, rs = r & 7;
            v16f acc;
            #pragma unroll
            for (int i = 0; i < 16; ++i) acc[i] = 0.0f;
            #pragma unroll
            for (int kf = 0; kf < 4; ++kf) {
                v8h fb = *(const v8h*)&sG1[r * 64 + ((kf * 2 + hi) ^ rs) * 8];
                acc = __builtin_amdgcn_mfma_f32_32x32x16_f16(fa[kf], fb, acc, 0, 0, 0);
            }
            #pragma unroll
            for (int q = 0; q < 4; ++q) {
                float4 b4 = *(const float4*)&sB1[w * 32 + 8 * q + 4 * hi];
                v4h hv;
                hv[0] = (_Float16)fmaxf(acc[q * 4 + 0] + b4.x, 0.0f);
                hv[1] = (_Float16)fmaxf(acc[q * 4 + 1] + b4.y, 0.0f);
                hv[2] = (_Float16)fmaxf(acc[q * 4 + 2] + b4.z, 0.0f);
                hv[3] = (_Float16)fmaxf(acc[q * 4 + 3] + b4.w, 0.0f);
                int gg = w * 4 + q;
                *(v4h*)&sH1[r * 128 + ((gg ^ rs) * 8) + 4 * hi] = hv;
            }
        }
        __syncthreads();

        if (g < 3) nbr_stage_g1(sG1, Cf, Qf, t, gpt0, g + 1, base, mi[g + 1]);

        // ---- a2 SWAPPED: mfma(data, weights) => D row=neighbor, col=channel.
        #pragma unroll
        for (int rt = 0; rt < 2; ++rt) {
            int r = rt * 32 + ln, rs = r & 7;
            v16f acc;
            #pragma unroll
            for (int i = 0; i < 16; ++i) acc[i] = 0.0f;
            #pragma unroll
            for (int kf = 0; kf < 8; ++kf) {
                v8h fb = *(const v8h*)&sH1[r * 128 + ((kf * 2 + hi) ^ rs) * 8];
                acc = __builtin_amdgcn_mfma_f32_32x32x16_f16(fb, fa2[kf], acc, 0, 0, 0);
            }
            // pool over 16 neighbors = D-rows
            float p0 = acc[0], p1 = acc[8];
            #pragma unroll
            for (int i = 1; i < 8; ++i) { p0 = fmaxf(p0, acc[i]); p1 = fmaxf(p1, acc[8 + i]); }
            p0 = fmaxf(p0, __shfl_xor(p0, 32));
            p1 = fmaxf(p1, __shfl_xor(p1, 32));
            float o0 = fmaxf(p0 + b2ch, 0.0f);
            float o1 = fmaxf(p1 + b2ch, 0.0f);
            if (hi == 0) {
                int p = g * 4 + rt * 2;
                sPool[p * 128 + w * 32 + ln]       = o0;
                sPool[(p + 1) * 128 + w * 32 + ln] = o1;
            }
        }
        __syncthreads();
    }

    {
        float* LOCAL = ws + LOCAL_OFF;
        const float4* sp4 = (const float4*)sPool;
        #pragma unroll
        for (int u = 0; u < 2; ++u) {
            int e = t + 256 * u;
            int pp = e >> 5, cc = e & 31;
            ((float4*)&LOCAL[(size_t)(gpt0 + pp) * 128])[cc] = sp4[e];
        }
    }

    if (t < 128) {
        float m = 0.0f;
        #pragma unroll
        for (int p = 0; p < 16; ++p) m = fmaxf(m, sPool[p * 128 + t]);
        atomicMax((int*)(ws + GF_OFF) + (blk >> 8) * 128 + t, __float_as_int(m));
    }
}

// ---------------------------------------------------------------------------
// Kernel 5: head c2/c3 fp16 MFMA + c4 fp32 — 8 waves/block (512 thr).
// ---------------------------------------------------------------------------
__global__ __launch_bounds__(512) void head_mfma_kernel(float* __restrict__ ws, float* __restrict__ out)
{
    __shared__ __align__(16) unsigned char smem[66560];
    _Float16* sF  = (_Float16*)smem;
    float*    sF3 = (float*)smem;
    _Float16* sF2 = (_Float16*)(smem + 33792);

    const int t  = threadIdx.x;
    const int l  = t & 63;
    const int w  = t >> 6;           // 0..7
    const int ln = l & 31;
    const int hi = l >> 5;
    const int gpt0 = blockIdx.x * 64;
    const int b = blockIdx.x >> 6;

    const float4* c2h = (const float4*)(ws + C2T_OFF);
    const float4* c3h = (const float4*)(ws + C3H_OFF);

    {
        int m = t >> 3, cs = t & 7;
        const float4* src = (cs < 4)
            ? (const float4*)(ws + LOCAL_OFF + (size_t)(gpt0 + m) * 128) + cs * 8
            : (const float4*)(ws + GF_OFF + b * 128) + (cs - 4) * 8;
        int gbase = cs * 4;
        #pragma unroll
        for (int u = 0; u < 4; ++u) {
            float4 a0 = src[u * 2], a1 = src[u * 2 + 1];
            v8h h;
            h[0] = (_Float16)a0.x; h[1] = (_Float16)a0.y;
            h[2] = (_Float16)a0.z; h[3] = (_Float16)a0.w;
            h[4] = (_Float16)a1.x; h[5] = (_Float16)a1.y;
            h[6] = (_Float16)a1.z; h[7] = (_Float16)a1.w;
            int g = (gbase + u) ^ (m & 31);
            *(v8h*)&sF[m * 256 + g * 8] = h;
        }
    }
    __syncthreads();

    // c2: one output tile per wave (ot2 = w, 0..7)
    {
        v8h fa[16];
        #pragma unroll
        for (int s = 0; s < 16; ++s) {
            float4 tmp = c2h[(w * 16 + s) * 64 + l];
            fa[s] = *(v8h*)&tmp;
        }
        float b2[16];
        #pragma unroll
        for (int i = 0; i < 16; ++i)
            b2[i] = ws[BC2_OFF + w * 32 + (i & 3) + 8 * (i >> 2) + 4 * hi];
        #pragma unroll
        for (int mt = 0; mt < 2; ++mt) {
            int m = mt * 32 + ln;
            v16f acc;
            #pragma unroll
            for (int i = 0; i < 16; ++i) acc[i] = 0.0f;
            #pragma unroll
            for (int s = 0; s < 16; ++s) {
                v8h fb = *(const v8h*)&sF[m * 256 + (((2 * s + hi) ^ ln) * 8)];
                acc = __builtin_amdgcn_mfma_f32_32x32x16_f16(fa[s], fb, acc, 0, 0, 0);
            }
            #pragma unroll
            for (int q = 0; q < 4; ++q) {
                v4h hv;
                #pragma unroll
                for (int j = 0; j < 4; ++j)
                    hv[j] = (_Float16)fmaxf(acc[q * 4 + j] + b2[q * 4 + j], 0.0f);
                *(v4h*)&sF2[m * 256 + (((w * 4 + q) ^ ln) * 8) + 4 * hi] = hv;
            }
        }
    }
    __syncthreads();

    // c3: (tile, m-half) = (w>>1, w&1)
    {
        int tw = w >> 1, mt = w & 1;
        v8h fa[16];
        #pragma unroll
        for (int s = 0; s < 16; ++s) {
            float4 tmp = c3h[(tw * 16 + s) * 64 + l];
            fa[s] = *(v8h*)&tmp;
        }
        float b3[16];
        #pragma unroll
        for (int i = 0; i < 16; ++i)
            b3[i] = ws[BC3_OFF + tw * 32 + (i & 3) + 8 * (i >> 2) + 4 * hi];
        int m = mt * 32 + ln;
        v16f acc;
        #pragma unroll
        for (int i = 0; i < 16; ++i) acc[i] = 0.0f;
        #pragma unroll
        for (int s = 0; s < 16; ++s) {
            v8h fb = *(const v8h*)&sF2[m * 256 + (((2 * s + hi) ^ ln) * 8)];
            acc = __builtin_amdgcn_mfma_f32_32x32x16_f16(fa[s], fb, acc, 0, 0, 0);
        }
        #pragma unroll
        for (int q = 0; q < 4; ++q) {
            float4 hv;
            hv.x = fmaxf(acc[q * 4 + 0] + b3[q * 4 + 0], 0.0f);
            hv.y = fmaxf(acc[q * 4 + 1] + b3[q * 4 + 1], 0.0f);
            hv.z = fmaxf(acc[q * 4 + 2] + b3[q * 4 + 2], 0.0f);
            hv.w = fmaxf(acc[q * 4 + 3] + b3[q * 4 + 3], 0.0f);
            *(float4*)&sF3[m * 132 + tw * 32 + q * 8 + 4 * hi] = hv;
        }
    }
    __syncthreads();

    const float* C4T = ws + C4T_OFF;
    for (int mo = t; mo < 384; mo += 512) {
        int m = mo / 6, o = mo - m * 6;
        float a = ws[BC4_OFF + o];
        const float4* f4 = (const float4*)(sF3 + m * 132);
        #pragma unroll 8
        for (int kq = 0; kq < 32; ++kq) {
            float4 f = f4[kq];
            a = fmaf(f.x, C4T[(kq * 4 + 0) * 6 + o], a);
            a = fmaf(f.y, C4T[(kq * 4 + 1) * 6 + o], a);
            a = fmaf(f.z, C4T[(kq * 4 + 2) * 6 + o], a);
            a = fmaf(f.w, C4T[(kq * 4 + 3) * 6 + o], a);
        }
        out[(size_t)(gpt0 + m) * 6 + o] = a;
    }
}

// ---------------------------------------------------------------------------
extern "C" void kernel_launch(void* const* d_in, const int* in_sizes, int n_in,
                              void* d_out, int out_size, void* d_ws, size_t ws_size,
                              hipStream_t stream)
{
    const float* pts = (const float*)d_in[0];
    float* ws = (float*)d_ws;
    float* out = (float*)d_out;

    fold_kernel<<<521, 256, 0, stream>>>(
        (const float*)d_in[1],  (const float*)d_in[2],  (const float*)d_in[3],  (const float*)d_in[4],  (const float*)d_in[5],  (const float*)d_in[6],
        (const float*)d_in[7],  (const float*)d_in[8],  (const float*)d_in[9],  (const float*)d_in[10], (const float*)d_in[11], (const float*)d_in[12],
        (const float*)d_in[13], (const float*)d_in[14], (const float*)d_in[15], (const float*)d_in[16], (const float*)d_in[17], (const float*)d_in[18],
        (const float*)d_in[19], (const float*)d_in[20], (const float*)d_in[21], (const float*)d_in[22], (const float*)d_in[23], (const float*)d_in[24],
        (const float*)d_in[25], (const float*)d_in[26], (const float*)d_in[27], (const float*)d_in[28], (const float*)d_in[29], (const float*)d_in[30],
        (const float*)d_in[31], (const float*)d_in[32], (const float*)d_in[33], (const float*)d_in[34], (const float*)d_in[35], (const float*)d_in[36],
        (const float*)d_in[37], (const float*)d_in[38], (const float*)d_in[39], (const float*)d_in[40], (const float*)d_in[41], (const float*)d_in[42],
        (const float*)d_in[43], (const float*)d_in[44],
        ws);

    point_mlp_kernel<<<2048, 256, 0, stream>>>(pts, ws);
    knn_kernel<<<512, 1024, 0, stream>>>(ws);
    nbr_mlp_mfma_kernel<<<2048, 256, 0, stream>>>(ws);
    head_mfma_kernel<<<512, 512, 0, stream>>>(ws, out);
}